// Round 9
// baseline (287.548 us; speedup 1.0000x reference)
//
#include <hip/hip_runtime.h>
#include <math.h>

// ---------------------------------------------------------------------------
// GuardNet: 2-layer attention-weighted GCN.
// R22: compress the two serial-phase tails via PURE granularity changes
// (no algorithm/layout change; R19's bucket restructure regressed, R21
// re-verified the R17 baseline at 253us):
//  - scatter range: EPB 2048->512 (1563 blocks = 6.1/CU, was 391 = 1.5/CU;
//    2 edges/thread). RPB/CAPB/ebuf layout untouched. Arithmetic: kernel1's
//    norm+gemm work drains in ~15us; the other ~30us is the 391-block
//    scatter tail on an idle machine.
//  - k_csr: TB 256->1024 (same 391 blocks, 16 waves/block, 2 edges/thread,
//    spart widened 4->16). Serial phases compress ~4x.
// Everything else byte-identical to R21 (= R17 session best).
// ---------------------------------------------------------------------------

#define ATT_CAP 96      // per-node LDS sim stash; deg>CAP falls back to recompute
#define EPB     512     // edges per bucket-sort block (= 2 per thread at TB=256)
#define RPB     128     // rows per bucket (bucket = row>>7)
#define NBUCK_MAX 512
#define CAPB    4096    // slack per bucket (mean 2048, sigma~45 -> never hit)

typedef _Float16 half4 __attribute__((ext_vector_type(4)));

// fused: blocks [0,nblkA) = bucket scatter; [nblkA, nblkA+nblkB) = fn row norm;
// [nblkA+nblkB, ...) = hd1 = x @ W1 (UNSCALED; k_att L1 epilogue applies di).
__global__ void k_bscat_norm_gemm(const int* __restrict__ row, const int* __restrict__ col,
                                  int* __restrict__ gcur, int* __restrict__ ebuf,
                                  int E, int nbuck, int nblkA, int nblkB,
                                  const float* __restrict__ x, float* __restrict__ fn,
                                  const float* __restrict__ W1, float* __restrict__ hd1,
                                  int N)
{
    __shared__ int lh[NBUCK_MAX];
    __shared__ int lbase[NBUCK_MAX];
    __shared__ float sW[64 * 64];    // 16 KB (gemm range only)
    __shared__ float sX[4 * 64];
    int b = blockIdx.x;
    int tid = threadIdx.x;
    if (b >= nblkA + nblkB) {
        // ---- W1 GEMM body: 4 rows/block, lane=output col, wave=row
        int gb = b - nblkA - nblkB;
        const float4* W4 = (const float4*)W1;
        float4* s4 = (float4*)sW;
#pragma unroll
        for (int i = 0; i < 4; ++i) s4[tid + 256 * i] = W4[tid + 256 * i];
        int base = gb * 4;
        {
            int rr = base + (tid >> 6);
            sX[tid] = (rr < N) ? x[(unsigned)rr * 64u + (unsigned)(tid & 63)] : 0.0f;
        }
        __syncthreads();
        int rl = tid >> 6, j = tid & 63;
        int r = base + rl;
        if (r < N) {
            float acc = 0.0f;
#pragma unroll
            for (int k = 0; k < 64; ++k) acc = fmaf(sX[rl * 64 + k], sW[k * 64 + j], acc);
            hd1[(unsigned)r * 64u + (unsigned)j] = acc;   // unscaled
        }
        return;
    }
    if (b >= nblkA) {
        // ---- normfn body
        int gid  = (b - nblkA) * blockDim.x + tid;
        int wid  = gid >> 6;
        int lane = tid & 63;
        if (wid >= N) return;
        float v = x[(unsigned)wid * 64u + (unsigned)lane];
        float s = v * v;
#pragma unroll
        for (int off = 32; off > 0; off >>= 1) s += __shfl_xor(s, off);
        float inv = rsqrtf(fmaxf(s, 1e-24f));
        fn[(unsigned)wid * 64u + (unsigned)lane] = v * inv;
        return;
    }
    // ---- bucket scatter body (EPB=512: 2 edges/thread, 1563 blocks)
    int ebeg = b * EPB;
    int rr[2], cc[2];
    for (int i = tid; i < nbuck; i += blockDim.x) lh[i] = 0;
    __syncthreads();
#pragma unroll
    for (int k = 0; k < 2; ++k) {
        int e = ebeg + k * 256 + tid;
        bool v = (e < E);
        int r = v ? row[e] : -1;
        int c = v ? col[e] : 0;
        rr[k] = r; cc[k] = c;
        if (v) atomicAdd(&lh[r >> 7], 1);
    }
    __syncthreads();
    for (int i = tid; i < nbuck; i += blockDim.x) {
        int cnt = lh[i];
        if (cnt) lbase[i] = i * CAPB + atomicAdd(gcur + i, cnt);
        lh[i] = 0;                       // reuse as local cursor
    }
    __syncthreads();
#pragma unroll
    for (int k = 0; k < 2; ++k) {
        int r = rr[k];
        if (r >= 0) {
            int j = r >> 7;
            int pos = lbase[j] + atomicAdd(&lh[j], 1);
            ebuf[pos] = ((r & (RPB - 1)) << 16) | cc[k];
        }
    }
}

// one block per bucket (391 blocks x 1024 threads): exclusive prefix of gcur,
// LDS row-binning of its ~2048-edge slack segment, coalesced col_s + rptr.
__global__ void k_csr(const int* __restrict__ ebuf, const int* __restrict__ gcur,
                      int* __restrict__ rptr, int* __restrict__ col_s,
                      int N, int E, int nbuck)
{
    __shared__ int pk[CAPB];
    __shared__ int lcol[CAPB];
    __shared__ int lcnt[RPB], lexc[RPB], lcur[RPB];
    __shared__ int spart[16];
    int j = blockIdx.x;
    int tid = threadIdx.x;
    int lane = tid & 63, wave = tid >> 6;

    // exclusive prefix: beg = sum(gcur[0..j))
    int part = 0;
    for (int i = tid; i < j; i += blockDim.x) part += gcur[i];
#pragma unroll
    for (int off = 32; off > 0; off >>= 1) part += __shfl_xor(part, off);
    if (lane == 0) spart[wave] = part;
    if (tid < RPB) lcnt[tid] = 0;
    __syncthreads();
    int beg = 0;
#pragma unroll
    for (int w2 = 0; w2 < 16; ++w2) beg += spart[w2];
    int m = gcur[j]; if (m > CAPB) m = CAPB;     // never hit

    const int* seg = ebuf + (size_t)j * CAPB;
    for (int i = tid; i < m; i += blockDim.x) pk[i] = seg[i];
    __syncthreads();
    for (int i = tid; i < m; i += blockDim.x) atomicAdd(&lcnt[pk[i] >> 16], 1);
    __syncthreads();
    if (tid < 64) {                    // wave 0 scans 128 counts (2 per lane)
        int a = lcnt[2 * tid], b2 = lcnt[2 * tid + 1];
        int s = a + b2;
        int incl = s;
#pragma unroll
        for (int off = 1; off < 64; off <<= 1) {
            int v = __shfl_up(incl, off);
            if (tid >= off) incl += v;
        }
        int base = incl - s;
        lexc[2 * tid] = base;     lexc[2 * tid + 1] = base + a;
        lcur[2 * tid] = base;     lcur[2 * tid + 1] = base + a;
    }
    __syncthreads();
    for (int i = tid; i < m; i += blockDim.x) {
        int v = pk[i];
        int p = atomicAdd(&lcur[v >> 16], 1);
        lcol[p] = v & 0xFFFF;
    }
    __syncthreads();
    for (int i = tid; i < m; i += blockDim.x) col_s[beg + i] = lcol[i];
    if (tid < RPB) {
        int r = j * RPB + tid;
        if (r < N) rptr[r] = beg + lexc[tid];
    }
    if (j == 0 && tid == 0) rptr[N] = E;
}

// fused attention: per node (wave): pass1 = edge cosine sims (4 lanes/edge,
// 16 edges/iter) stashed in LDS + wave-reduced row-sum; pass2 = w=exp(sim/rs),
// ballot-rank compaction into packed cw=(col,w), lend/dinv/selfc. No atomics.
// Epilogues (wave-uniform di): L1: hsc row *= di (scales hd1 in place);
// L2: hd2[wid] = g2[wid] * di (fp16).
__global__ void k_att(const float* __restrict__ fn,
                      const int* __restrict__ rptr, const int* __restrict__ col_s,
                      int2* __restrict__ cw, int* __restrict__ lend,
                      float* __restrict__ dinv, float* __restrict__ selfc,
                      const float* __restrict__ g2, _Float16* __restrict__ hd2,
                      float* __restrict__ hsc, int n)
{
    __shared__ float ssim[4][ATT_CAP];
    __shared__ int   scol[4][ATT_CAP];
    int wib  = threadIdx.x >> 6;
    int wid  = blockIdx.x * 4 + wib;
    int lane = threadIdx.x & 63;
    if (wid >= n) return;
    int sub = lane & 3;       // lane within 4-lane edge group
    int grp = lane >> 2;      // edge group 0..15
    int beg = rptr[wid], end = rptr[wid + 1];
    int deg_all = end - beg;

    const float4* frp = (const float4*)fn;
    unsigned rbase = (unsigned)wid * 16u;        // float4 index of own row
    float4 a0 = frp[rbase + sub],     a1 = frp[rbase + sub + 4],
           a2 = frp[rbase + sub + 8], a3 = frp[rbase + sub + 12];

    // pass 1: sims + row-sum (16 edges per iteration)
    float rs_part = 0.0f;
    int ngrp = (deg_all + 15) >> 4;
    for (int g = 0; g < ngrp; ++g) {
        int li = g * 16 + grp;
        float s = 0.0f; int c = 0;
        bool valid = (li < deg_all);
        if (valid) {
            c = col_s[beg + li];
            unsigned cb = (unsigned)c * 16u;     // 32-bit float4 index
            float4 b0 = frp[cb + sub],     b1 = frp[cb + sub + 4],
                   b2 = frp[cb + sub + 8], b3 = frp[cb + sub + 12];
            float p = a0.x * b0.x + a0.y * b0.y + a0.z * b0.z + a0.w * b0.w
                    + a1.x * b1.x + a1.y * b1.y + a1.z * b1.z + a1.w * b1.w
                    + a2.x * b2.x + a2.y * b2.y + a2.z * b2.z + a2.w * b2.w
                    + a3.x * b3.x + a3.y * b3.y + a3.z * b3.z + a3.w * b3.w;
            p += __shfl_xor(p, 1);
            p += __shfl_xor(p, 2);
            s = (p < 0.1f) ? 0.0f : p;
        }
        if (sub == 0 && valid) {
            if (li < ATT_CAP) { ssim[wib][li] = s; scol[wib][li] = c; }
            if (s > 0.0f) rs_part += s;
        }
    }
#pragma unroll
    for (int off = 32; off > 0; off >>= 1) rs_part += __shfl_xor(rs_part, off);
    float denom = fmaxf(rs_part, 1e-12f);

    // pass 2: weights + live compaction (lane = edge index within 64-chunk)
    int   nlive = 0;
    float sw_lane = 0.0f;
    for (int base = 0; base < deg_all; base += 64) {
        int li = base + lane;
        bool valid = (li < deg_all);
        float s = 0.0f; int c = 0;
        if (valid) {
            if (li < ATT_CAP) { s = ssim[wib][li]; c = scol[wib][li]; }
            else {                           // astronomically rare: per-lane dot
                c = col_s[beg + li];
                const float* fr = fn + (size_t)wid * 64;
                const float* fc = fn + (size_t)c * 64;
                float p = 0.0f;
                for (int k = 0; k < 64; ++k) p += fr[k] * fc[k];
                s = (p < 0.1f) ? 0.0f : p;
            }
        }
        float w = (valid && s > 0.0f) ? __expf(s / denom) : 0.0f;
        unsigned long long M = __ballot(w > 0.0f);
        int rank = __popcll(M & ((1ull << lane) - 1ull));
        if (w > 0.0f) {
            int2 pw; pw.x = c; pw.y = __float_as_int(w);
            cw[beg + nlive + rank] = pw;
            sw_lane += w;
        }
        nlive += __popcll(M);
    }
#pragma unroll
    for (int off = 32; off > 0; off >>= 1) sw_lane += __shfl_xor(sw_lane, off);

    // post-reduction values are wave-uniform: all lanes compute di
    float wself = __expf(1.0f / ((float)nlive + 1.0f));
    float D  = sw_lane + wself;
    float di = rsqrtf(fmaxf(D, 1e-12f));
    if (lane == 0) {
        lend[wid]  = beg + nlive;
        dinv[wid]  = di;
        selfc[wid] = wself * di;   // self term applied to dinv-scaled table
    }
    if (hsc)                       // layer-1: scale hd1 row in place by di
        hsc[(unsigned)wid * 64u + (unsigned)lane] *= di;
    if (g2 && lane < 40)           // layer-2: hd2 = g2 * di (fp16)
        hd2[(unsigned)wid * 40u + (unsigned)lane] =
            (_Float16)(g2[(unsigned)wid * 40u + (unsigned)lane] * di);
}

// transposed live-edge aggregation, generic vec4 element (float4 / half4):
// 4 edges x 16 lanes; lane (eg,q) loads one vec4 of row c_eg at feature q*4.
// 4-deep software pipeline (prefetch 4 edge-quads, unrolled consume with
// rolling refill); 32-bit gather indexing (tables < 2^32 bytes).
// Returns per-lane (lane=feature) weighted sum via xor-reduce + transpose.
template <int F, typename Vec4>
__device__ inline float agg_core_t(const Vec4* __restrict__ hdv,
                                   const int2* __restrict__ cw,
                                   int beg, int lend_, int lane)
{
    int q  = lane & 15;
    int eg = lane >> 4;
    bool qact = (F == 64) ? true : (q < (F >> 2));
    constexpr unsigned FQ = F >> 2;
    float acc0 = 0.f, acc1 = 0.f, acc2 = 0.f, acc3 = 0.f;
    for (int base = beg; base < lend_; base += 64) {
        int idx = base + lane;
        int cv = 0; float wv = 0.0f;
        if (idx < lend_) { int2 pw = cw[(unsigned)idx]; cv = pw.x; wv = __int_as_float(pw.y); }
        int cnt = lend_ - base; if (cnt > 64) cnt = 64;
        int nit = (cnt + 3) >> 2;            // 1..16 edge-quads (wave-uniform)

        Vec4  hv[4] = {};                    // 4 gathers in flight
        float wj[4] = {};
#pragma unroll
        for (int p = 0; p < 4; ++p) {        // prefetch: issue all before use
            int c = __shfl(cv, 4 * p + eg);  // beyond-cnt lanes hold cv=0,wv=0
            wj[p] = __shfl(wv, 4 * p + eg);
            if (qact && p < nit) hv[p] = hdv[(unsigned)c * FQ + (unsigned)q];
        }
#pragma unroll
        for (int it = 0; it < 16; ++it) {    // unrolled: it&3 is compile-time
            if (it < nit) {
                float w = wj[it & 3];
                Vec4  h = hv[it & 3];
                acc0 += w * (float)h.x;
                acc1 += w * (float)h.y;
                acc2 += w * (float)h.z;
                acc3 += w * (float)h.w;
                if (it + 4 < nit) {          // rolling refill (uniform guard)
                    int jn = 4 * (it + 4);
                    int c = __shfl(cv, jn + eg);
                    wj[it & 3] = __shfl(wv, jn + eg);
                    if (qact) hv[it & 3] = hdv[(unsigned)c * FQ + (unsigned)q];
                }
            }
        }
    }
    acc0 += __shfl_xor(acc0, 16); acc0 += __shfl_xor(acc0, 32);
    acc1 += __shfl_xor(acc1, 16); acc1 += __shfl_xor(acc1, 32);
    acc2 += __shfl_xor(acc2, 16); acc2 += __shfl_xor(acc2, 32);
    acc3 += __shfl_xor(acc3, 16); acc3 += __shfl_xor(acc3, 32);
    int srcq = lane >> 2;
    float a0 = __shfl(acc0, srcq);
    float a1 = __shfl(acc1, srcq);
    float a2 = __shfl(acc2, srcq);
    float a3 = __shfl(acc3, srcq);
    int k = lane & 3;
    return (k == 0) ? a0 : (k == 1) ? a1 : (k == 2) ? a2 : a3;
}

// layer-1 aggregation over fp32 dinv-scaled table + relu; emits fnh (att2)
// and fused g2 = v @ W2. 8 nodes/block (2 per wave): keeps 8x W2-staging
// amortization while doubling block-level parallelism (6250 blocks, 24.4/CU).
__global__ void k_agg64(const float* __restrict__ hd, const int2* __restrict__ cw,
                        const float* __restrict__ dinv, const float* __restrict__ selfc,
                        const float* __restrict__ b, const int* __restrict__ row_ptr,
                        const int* __restrict__ lend, const float* __restrict__ W2,
                        float* __restrict__ g2, float* __restrict__ fnh, int n)
{
    __shared__ float sW2[64 * 40];   // 10 KB, staged once per block (8 nodes)
    __shared__ float sv[4][64];
    int tid = threadIdx.x;
    {
        const float4* W4 = (const float4*)W2;
        float4* s4 = (float4*)sW2;
        for (int i = tid; i < 64 * 40 / 4; i += 256) s4[i] = W4[i];
    }
    __syncthreads();

    int lane = tid & 63;
    int wib  = tid >> 6;
    float bl = b[lane];              // hoisted: same for both t iterations
    for (int t = 0; t < 2; ++t) {
        int wid = blockIdx.x * 8 + wib * 2 + t;
        if (wid >= n) break;
        int beg = row_ptr[wid], le = lend[wid];
        // independent loads issued BEFORE the gather so LLC latency overlaps
        float hs = hd[(unsigned)wid * 64u + (unsigned)lane];  // = h*di
        float dv = dinv[wid];
        float sc = selfc[wid];
        float accf = agg_core_t<64>((const float4*)hd, cw, beg, le, lane);
        float v = dv * accf + sc * hs + bl;
        v = fmaxf(v, 0.0f); // relu
        float s = v * v;
#pragma unroll
        for (int off = 32; off > 0; off >>= 1) s += __shfl_xor(s, off);
        float inv = rsqrtf(fmaxf(s, 1e-24f));
        fnh[(unsigned)wid * 64u + (unsigned)lane] = v * inv;

        // fused v @ W2 (within-wave LDS exchange; no block barrier needed)
        sv[wib][lane] = v;
        if (lane < 40) {
            float acc = 0.0f;
#pragma unroll
            for (int k = 0; k < 64; ++k) acc = fmaf(sv[wib][k], sW2[k * 40 + lane], acc);
            g2[(unsigned)wid * 40u + (unsigned)lane] = acc;
        }
    }
}

// layer-2 aggregation (F=40, fp16 table) + bias + log_softmax -> output.
__global__ void k_agg40_lsm(const _Float16* __restrict__ hd2, const int2* __restrict__ cw,
                            const float* __restrict__ dinv, const float* __restrict__ selfc,
                            const float* __restrict__ b, const int* __restrict__ row_ptr,
                            const int* __restrict__ lend,
                            float* __restrict__ out, int n)
{
    constexpr int F = 40;
    int gid  = blockIdx.x * blockDim.x + threadIdx.x;
    int wid  = gid >> 6;
    int lane = threadIdx.x & 63;
    if (wid >= n) return;
    int beg = row_ptr[wid], le = lend[wid];
    bool active = (lane < F);
    // independent loads issued before the gather
    float hs = active ? (float)hd2[(unsigned)wid * 40u + (unsigned)lane] : 0.0f;
    float dv = dinv[wid];
    float sc = selfc[wid];
    float bl = active ? b[lane] : 0.0f;
    float accf = agg_core_t<F>((const half4*)hd2, cw, beg, le, lane);
    float v = 0.0f;
    if (active) v = dv * accf + sc * hs + bl;
    float m = active ? v : -__builtin_inff();
#pragma unroll
    for (int off = 32; off > 0; off >>= 1) m = fmaxf(m, __shfl_xor(m, off));
    float ex = active ? __expf(v - m) : 0.0f;
    float s = ex;
#pragma unroll
    for (int off = 32; off > 0; off >>= 1) s += __shfl_xor(s, off);
    if (active) out[(size_t)wid * F + lane] = v - m - __logf(s);
}

extern "C" void kernel_launch(void* const* d_in, const int* in_sizes, int n_in,
                              void* d_out, int out_size, void* d_ws, size_t ws_size,
                              hipStream_t stream)
{
    const float* x  = (const float*)d_in[0];
    const int*   ei = (const int*)d_in[1];
    const float* W1 = (const float*)d_in[2];
    const float* b1 = (const float*)d_in[3];
    const float* W2 = (const float*)d_in[4];
    const float* b2 = (const float*)d_in[5];
    float* out = (float*)d_out;

    const int N = in_sizes[0] / 64;   // 50000
    const int E = in_sizes[1] / 2;    // 800000
    const int* row = ei;
    const int* col = ei + E;

    const int nblkA = (E + EPB - 1) / EPB;       // 1563 edge blocks (bucket sort)
    const int nbuck = (N + RPB - 1) / RPB;       // 391 buckets (rows/128)

    char* p = (char*)d_ws;
    auto alloc = [&](size_t bytes) -> char* {
        char* r = p; p += (bytes + 255) & ~(size_t)255; return r;
    };
    float*     fn     = (float*)alloc((size_t)N * 64 * 4);     // normalized x
    float*     dinv   = (float*)alloc((size_t)N * 4);
    float*     selfc  = (float*)alloc((size_t)N * 4);
    float*     hd1    = (float*)alloc((size_t)N * 64 * 4);     // x@W1, then *di in-place
    float*     g2     = (float*)alloc((size_t)N * 40 * 4);     // hrelu@W2 (fp32)
    _Float16*  hd2    = (_Float16*)alloc((size_t)N * 40 * 2);  // g2*di2 (fp16)
    float*     fnh    = (float*)alloc((size_t)N * 64 * 4);     // normalized hrelu
    int*       rptr   = (int*)alloc((size_t)(N + 1) * 4);
    int*       lendv  = (int*)alloc((size_t)N * 4);
    int*       col_s  = (int*)alloc((size_t)E * 4);
    int2*      cw     = (int2*)alloc((size_t)E * 8);           // packed (col,w)
    int*       ebuf   = (int*)alloc((size_t)nbuck * CAPB * 4); // slack-segmented
    int*       gcur   = (int*)alloc((size_t)nbuck * 4);

    const int TB = 256;
    int blk_nodeWave = (N * 64 + TB - 1) / TB;   // 12500 (norm range, 1 wave/node)
    int blk_gemm     = (N + 3) / 4;              // 12500 (gemm range, 4 rows/block)
    int blk_node4    = (N + 3) / 4;              // 12500
    int blk_node8    = (N + 7) / 8;              // 6250

    hipMemsetAsync(gcur, 0, (size_t)nbuck * 4, stream);

    // ---- CSR build + x normalization + W1 GEMM (fused 3-range launch)
    k_bscat_norm_gemm<<<nblkA + blk_nodeWave + blk_gemm, TB, 0, stream>>>(
        row, col, gcur, ebuf, E, nbuck, nblkA, blk_nodeWave, x, fn, W1, hd1, N);
    k_csr<<<nbuck, 1024, 0, stream>>>(ebuf, gcur, rptr, col_s, N, E, nbuck);

    // ---- layer 1 (att epilogue scales hd1 *= di in place)
    k_att<<<blk_node4, TB, 0, stream>>>(fn, rptr, col_s, cw, lendv, dinv, selfc,
                                        (const float*)nullptr, (_Float16*)nullptr,
                                        hd1, N);
    k_agg64<<<blk_node8, TB, 0, stream>>>(hd1, cw, dinv, selfc, b1,
                                          rptr, lendv, W2, g2, fnh, N);

    // ---- layer 2 (att epilogue scales g2 -> hd2; agg40 finishes)
    k_att<<<blk_node4, TB, 0, stream>>>(fnh, rptr, col_s, cw, lendv, dinv, selfc,
                                        g2, hd2, (float*)nullptr, N);
    k_agg40_lsm<<<blk_nodeWave, TB, 0, stream>>>(hd2, cw, dinv, selfc, b2,
                                                 rptr, lendv, out, N);
}

// Round 10
// 250.436 us; speedup vs baseline: 1.1482x; 1.1482x over previous
//
#include <hip/hip_runtime.h>
#include <math.h>

// ---------------------------------------------------------------------------
// GuardNet: 2-layer attention-weighted GCN.
// R23: byte-identical revert to R21/R17 (session best, 251.9/253.3us, twice
// verified). R22's EPB=512 falsified the scatter-tail theory: per-block
// bucket bookkeeping (391-entry zero/scan + ~340 gcur atomics per 512-edge
// block) quadrupled and kernel1 went 47->85us. Ledger: R15/R16/R19/R22
// (sched/occupancy/granularity) flat-or-regressed; R18/R20 (CSR algo,
// precision) catastrophic; R17 (launch fusion) is the only structural win.
//  - W1 GEMM fused into launch 1 as a 3rd block range (unscaled out);
//    k_att(L1) epilogue scales hd1 *= di in place.
//  - __expf/__logf/rsqrtf in hot transcendental paths.
//  - k_agg64: 8 nodes/block, 4-deep pipelined gather, 32-bit indexing.
// ---------------------------------------------------------------------------

#define ATT_CAP 96      // per-node LDS sim stash; deg>CAP falls back to recompute
#define EPB     2048    // edges per bucket-sort block (= 8 per thread at TB=256)
#define RPB     128     // rows per bucket (bucket = row>>7)
#define NBUCK_MAX 512
#define CAPB    4096    // slack per bucket (mean 2048, sigma~45 -> never hit)

typedef _Float16 half4 __attribute__((ext_vector_type(4)));

// fused: blocks [0,nblkA) = bucket scatter; [nblkA, nblkA+nblkB) = fn row norm;
// [nblkA+nblkB, ...) = hd1 = x @ W1 (UNSCALED; k_att L1 epilogue applies di).
__global__ void k_bscat_norm_gemm(const int* __restrict__ row, const int* __restrict__ col,
                                  int* __restrict__ gcur, int* __restrict__ ebuf,
                                  int E, int nbuck, int nblkA, int nblkB,
                                  const float* __restrict__ x, float* __restrict__ fn,
                                  const float* __restrict__ W1, float* __restrict__ hd1,
                                  int N)
{
    __shared__ int lh[NBUCK_MAX];
    __shared__ int lbase[NBUCK_MAX];
    __shared__ float sW[64 * 64];    // 16 KB (gemm range only)
    __shared__ float sX[4 * 64];
    int b = blockIdx.x;
    int tid = threadIdx.x;
    if (b >= nblkA + nblkB) {
        // ---- W1 GEMM body: 4 rows/block, lane=output col, wave=row
        int gb = b - nblkA - nblkB;
        const float4* W4 = (const float4*)W1;
        float4* s4 = (float4*)sW;
#pragma unroll
        for (int i = 0; i < 4; ++i) s4[tid + 256 * i] = W4[tid + 256 * i];
        int base = gb * 4;
        {
            int rr = base + (tid >> 6);
            sX[tid] = (rr < N) ? x[(unsigned)rr * 64u + (unsigned)(tid & 63)] : 0.0f;
        }
        __syncthreads();
        int rl = tid >> 6, j = tid & 63;
        int r = base + rl;
        if (r < N) {
            float acc = 0.0f;
#pragma unroll
            for (int k = 0; k < 64; ++k) acc = fmaf(sX[rl * 64 + k], sW[k * 64 + j], acc);
            hd1[(unsigned)r * 64u + (unsigned)j] = acc;   // unscaled
        }
        return;
    }
    if (b >= nblkA) {
        // ---- normfn body
        int gid  = (b - nblkA) * blockDim.x + tid;
        int wid  = gid >> 6;
        int lane = tid & 63;
        if (wid >= N) return;
        float v = x[(unsigned)wid * 64u + (unsigned)lane];
        float s = v * v;
#pragma unroll
        for (int off = 32; off > 0; off >>= 1) s += __shfl_xor(s, off);
        float inv = rsqrtf(fmaxf(s, 1e-24f));
        fn[(unsigned)wid * 64u + (unsigned)lane] = v * inv;
        return;
    }
    // ---- bucket scatter body
    int ebeg = b * EPB;
    int rr[8], cc[8];
    for (int i = tid; i < nbuck; i += blockDim.x) lh[i] = 0;
    __syncthreads();
#pragma unroll
    for (int k = 0; k < 8; ++k) {
        int e = ebeg + k * 256 + tid;
        bool v = (e < E);
        int r = v ? row[e] : -1;
        int c = v ? col[e] : 0;
        rr[k] = r; cc[k] = c;
        if (v) atomicAdd(&lh[r >> 7], 1);
    }
    __syncthreads();
    for (int i = tid; i < nbuck; i += blockDim.x) {
        int cnt = lh[i];
        if (cnt) lbase[i] = i * CAPB + atomicAdd(gcur + i, cnt);
        lh[i] = 0;                       // reuse as local cursor
    }
    __syncthreads();
#pragma unroll
    for (int k = 0; k < 8; ++k) {
        int r = rr[k];
        if (r >= 0) {
            int j = r >> 7;
            int pos = lbase[j] + atomicAdd(&lh[j], 1);
            ebuf[pos] = ((r & (RPB - 1)) << 16) | cc[k];
        }
    }
}

// one block per bucket: computes own exclusive prefix of gcur, LDS row-binning
// of its slack segment, coalesced col_s + rptr writes.
__global__ void k_csr(const int* __restrict__ ebuf, const int* __restrict__ gcur,
                      int* __restrict__ rptr, int* __restrict__ col_s,
                      int N, int E, int nbuck)
{
    __shared__ int pk[CAPB];
    __shared__ int lcol[CAPB];
    __shared__ int lcnt[RPB], lexc[RPB], lcur[RPB];
    __shared__ int spart[4];
    int j = blockIdx.x;
    int tid = threadIdx.x;
    int lane = tid & 63, wave = tid >> 6;

    // exclusive prefix: beg = sum(gcur[0..j))
    int part = 0;
    for (int i = tid; i < j; i += blockDim.x) part += gcur[i];
#pragma unroll
    for (int off = 32; off > 0; off >>= 1) part += __shfl_xor(part, off);
    if (lane == 0) spart[wave] = part;
    if (tid < RPB) lcnt[tid] = 0;
    __syncthreads();
    int beg = spart[0] + spart[1] + spart[2] + spart[3];
    int m = gcur[j]; if (m > CAPB) m = CAPB;     // never hit

    const int* seg = ebuf + (size_t)j * CAPB;
    for (int i = tid; i < m; i += blockDim.x) pk[i] = seg[i];
    __syncthreads();
    for (int i = tid; i < m; i += blockDim.x) atomicAdd(&lcnt[pk[i] >> 16], 1);
    __syncthreads();
    if (tid < 64) {                    // wave 0 scans 128 counts (2 per lane)
        int a = lcnt[2 * tid], b2 = lcnt[2 * tid + 1];
        int s = a + b2;
        int incl = s;
#pragma unroll
        for (int off = 1; off < 64; off <<= 1) {
            int v = __shfl_up(incl, off);
            if (tid >= off) incl += v;
        }
        int base = incl - s;
        lexc[2 * tid] = base;     lexc[2 * tid + 1] = base + a;
        lcur[2 * tid] = base;     lcur[2 * tid + 1] = base + a;
    }
    __syncthreads();
    for (int i = tid; i < m; i += blockDim.x) {
        int v = pk[i];
        int p = atomicAdd(&lcur[v >> 16], 1);
        lcol[p] = v & 0xFFFF;
    }
    __syncthreads();
    for (int i = tid; i < m; i += blockDim.x) col_s[beg + i] = lcol[i];
    if (tid < RPB) {
        int r = j * RPB + tid;
        if (r < N) rptr[r] = beg + lexc[tid];
    }
    if (j == 0 && tid == 0) rptr[N] = E;
}

// fused attention: per node (wave): pass1 = edge cosine sims (4 lanes/edge,
// 16 edges/iter) stashed in LDS + wave-reduced row-sum; pass2 = w=exp(sim/rs),
// ballot-rank compaction into packed cw=(col,w), lend/dinv/selfc. No atomics.
// Epilogues (wave-uniform di): L1: hsc row *= di (scales hd1 in place);
// L2: hd2[wid] = g2[wid] * di (fp16).
__global__ void k_att(const float* __restrict__ fn,
                      const int* __restrict__ rptr, const int* __restrict__ col_s,
                      int2* __restrict__ cw, int* __restrict__ lend,
                      float* __restrict__ dinv, float* __restrict__ selfc,
                      const float* __restrict__ g2, _Float16* __restrict__ hd2,
                      float* __restrict__ hsc, int n)
{
    __shared__ float ssim[4][ATT_CAP];
    __shared__ int   scol[4][ATT_CAP];
    int wib  = threadIdx.x >> 6;
    int wid  = blockIdx.x * 4 + wib;
    int lane = threadIdx.x & 63;
    if (wid >= n) return;
    int sub = lane & 3;       // lane within 4-lane edge group
    int grp = lane >> 2;      // edge group 0..15
    int beg = rptr[wid], end = rptr[wid + 1];
    int deg_all = end - beg;

    const float4* frp = (const float4*)fn;
    unsigned rbase = (unsigned)wid * 16u;        // float4 index of own row
    float4 a0 = frp[rbase + sub],     a1 = frp[rbase + sub + 4],
           a2 = frp[rbase + sub + 8], a3 = frp[rbase + sub + 12];

    // pass 1: sims + row-sum (16 edges per iteration)
    float rs_part = 0.0f;
    int ngrp = (deg_all + 15) >> 4;
    for (int g = 0; g < ngrp; ++g) {
        int li = g * 16 + grp;
        float s = 0.0f; int c = 0;
        bool valid = (li < deg_all);
        if (valid) {
            c = col_s[beg + li];
            unsigned cb = (unsigned)c * 16u;     // 32-bit float4 index
            float4 b0 = frp[cb + sub],     b1 = frp[cb + sub + 4],
                   b2 = frp[cb + sub + 8], b3 = frp[cb + sub + 12];
            float p = a0.x * b0.x + a0.y * b0.y + a0.z * b0.z + a0.w * b0.w
                    + a1.x * b1.x + a1.y * b1.y + a1.z * b1.z + a1.w * b1.w
                    + a2.x * b2.x + a2.y * b2.y + a2.z * b2.z + a2.w * b2.w
                    + a3.x * b3.x + a3.y * b3.y + a3.z * b3.z + a3.w * b3.w;
            p += __shfl_xor(p, 1);
            p += __shfl_xor(p, 2);
            s = (p < 0.1f) ? 0.0f : p;
        }
        if (sub == 0 && valid) {
            if (li < ATT_CAP) { ssim[wib][li] = s; scol[wib][li] = c; }
            if (s > 0.0f) rs_part += s;
        }
    }
#pragma unroll
    for (int off = 32; off > 0; off >>= 1) rs_part += __shfl_xor(rs_part, off);
    float denom = fmaxf(rs_part, 1e-12f);

    // pass 2: weights + live compaction (lane = edge index within 64-chunk)
    int   nlive = 0;
    float sw_lane = 0.0f;
    for (int base = 0; base < deg_all; base += 64) {
        int li = base + lane;
        bool valid = (li < deg_all);
        float s = 0.0f; int c = 0;
        if (valid) {
            if (li < ATT_CAP) { s = ssim[wib][li]; c = scol[wib][li]; }
            else {                           // astronomically rare: per-lane dot
                c = col_s[beg + li];
                const float* fr = fn + (size_t)wid * 64;
                const float* fc = fn + (size_t)c * 64;
                float p = 0.0f;
                for (int k = 0; k < 64; ++k) p += fr[k] * fc[k];
                s = (p < 0.1f) ? 0.0f : p;
            }
        }
        float w = (valid && s > 0.0f) ? __expf(s / denom) : 0.0f;
        unsigned long long M = __ballot(w > 0.0f);
        int rank = __popcll(M & ((1ull << lane) - 1ull));
        if (w > 0.0f) {
            int2 pw; pw.x = c; pw.y = __float_as_int(w);
            cw[beg + nlive + rank] = pw;
            sw_lane += w;
        }
        nlive += __popcll(M);
    }
#pragma unroll
    for (int off = 32; off > 0; off >>= 1) sw_lane += __shfl_xor(sw_lane, off);

    // post-reduction values are wave-uniform: all lanes compute di
    float wself = __expf(1.0f / ((float)nlive + 1.0f));
    float D  = sw_lane + wself;
    float di = rsqrtf(fmaxf(D, 1e-12f));
    if (lane == 0) {
        lend[wid]  = beg + nlive;
        dinv[wid]  = di;
        selfc[wid] = wself * di;   // self term applied to dinv-scaled table
    }
    if (hsc)                       // layer-1: scale hd1 row in place by di
        hsc[(unsigned)wid * 64u + (unsigned)lane] *= di;
    if (g2 && lane < 40)           // layer-2: hd2 = g2 * di (fp16)
        hd2[(unsigned)wid * 40u + (unsigned)lane] =
            (_Float16)(g2[(unsigned)wid * 40u + (unsigned)lane] * di);
}

// transposed live-edge aggregation, generic vec4 element (float4 / half4):
// 4 edges x 16 lanes; lane (eg,q) loads one vec4 of row c_eg at feature q*4.
// 4-deep software pipeline (prefetch 4 edge-quads, unrolled consume with
// rolling refill); 32-bit gather indexing (tables < 2^32 bytes).
// Returns per-lane (lane=feature) weighted sum via xor-reduce + transpose.
template <int F, typename Vec4>
__device__ inline float agg_core_t(const Vec4* __restrict__ hdv,
                                   const int2* __restrict__ cw,
                                   int beg, int lend_, int lane)
{
    int q  = lane & 15;
    int eg = lane >> 4;
    bool qact = (F == 64) ? true : (q < (F >> 2));
    constexpr unsigned FQ = F >> 2;
    float acc0 = 0.f, acc1 = 0.f, acc2 = 0.f, acc3 = 0.f;
    for (int base = beg; base < lend_; base += 64) {
        int idx = base + lane;
        int cv = 0; float wv = 0.0f;
        if (idx < lend_) { int2 pw = cw[(unsigned)idx]; cv = pw.x; wv = __int_as_float(pw.y); }
        int cnt = lend_ - base; if (cnt > 64) cnt = 64;
        int nit = (cnt + 3) >> 2;            // 1..16 edge-quads (wave-uniform)

        Vec4  hv[4] = {};                    // 4 gathers in flight
        float wj[4] = {};
#pragma unroll
        for (int p = 0; p < 4; ++p) {        // prefetch: issue all before use
            int c = __shfl(cv, 4 * p + eg);  // beyond-cnt lanes hold cv=0,wv=0
            wj[p] = __shfl(wv, 4 * p + eg);
            if (qact && p < nit) hv[p] = hdv[(unsigned)c * FQ + (unsigned)q];
        }
#pragma unroll
        for (int it = 0; it < 16; ++it) {    // unrolled: it&3 is compile-time
            if (it < nit) {
                float w = wj[it & 3];
                Vec4  h = hv[it & 3];
                acc0 += w * (float)h.x;
                acc1 += w * (float)h.y;
                acc2 += w * (float)h.z;
                acc3 += w * (float)h.w;
                if (it + 4 < nit) {          // rolling refill (uniform guard)
                    int jn = 4 * (it + 4);
                    int c = __shfl(cv, jn + eg);
                    wj[it & 3] = __shfl(wv, jn + eg);
                    if (qact) hv[it & 3] = hdv[(unsigned)c * FQ + (unsigned)q];
                }
            }
        }
    }
    acc0 += __shfl_xor(acc0, 16); acc0 += __shfl_xor(acc0, 32);
    acc1 += __shfl_xor(acc1, 16); acc1 += __shfl_xor(acc1, 32);
    acc2 += __shfl_xor(acc2, 16); acc2 += __shfl_xor(acc2, 32);
    acc3 += __shfl_xor(acc3, 16); acc3 += __shfl_xor(acc3, 32);
    int srcq = lane >> 2;
    float a0 = __shfl(acc0, srcq);
    float a1 = __shfl(acc1, srcq);
    float a2 = __shfl(acc2, srcq);
    float a3 = __shfl(acc3, srcq);
    int k = lane & 3;
    return (k == 0) ? a0 : (k == 1) ? a1 : (k == 2) ? a2 : a3;
}

// layer-1 aggregation over fp32 dinv-scaled table + relu; emits fnh (att2)
// and fused g2 = v @ W2. 8 nodes/block (2 per wave): keeps 8x W2-staging
// amortization while doubling block-level parallelism (6250 blocks, 24.4/CU).
__global__ void k_agg64(const float* __restrict__ hd, const int2* __restrict__ cw,
                        const float* __restrict__ dinv, const float* __restrict__ selfc,
                        const float* __restrict__ b, const int* __restrict__ row_ptr,
                        const int* __restrict__ lend, const float* __restrict__ W2,
                        float* __restrict__ g2, float* __restrict__ fnh, int n)
{
    __shared__ float sW2[64 * 40];   // 10 KB, staged once per block (8 nodes)
    __shared__ float sv[4][64];
    int tid = threadIdx.x;
    {
        const float4* W4 = (const float4*)W2;
        float4* s4 = (float4*)sW2;
        for (int i = tid; i < 64 * 40 / 4; i += 256) s4[i] = W4[i];
    }
    __syncthreads();

    int lane = tid & 63;
    int wib  = tid >> 6;
    float bl = b[lane];              // hoisted: same for both t iterations
    for (int t = 0; t < 2; ++t) {
        int wid = blockIdx.x * 8 + wib * 2 + t;
        if (wid >= n) break;
        int beg = row_ptr[wid], le = lend[wid];
        // independent loads issued BEFORE the gather so LLC latency overlaps
        float hs = hd[(unsigned)wid * 64u + (unsigned)lane];  // = h*di
        float dv = dinv[wid];
        float sc = selfc[wid];
        float accf = agg_core_t<64>((const float4*)hd, cw, beg, le, lane);
        float v = dv * accf + sc * hs + bl;
        v = fmaxf(v, 0.0f); // relu
        float s = v * v;
#pragma unroll
        for (int off = 32; off > 0; off >>= 1) s += __shfl_xor(s, off);
        float inv = rsqrtf(fmaxf(s, 1e-24f));
        fnh[(unsigned)wid * 64u + (unsigned)lane] = v * inv;

        // fused v @ W2 (within-wave LDS exchange; no block barrier needed)
        sv[wib][lane] = v;
        if (lane < 40) {
            float acc = 0.0f;
#pragma unroll
            for (int k = 0; k < 64; ++k) acc = fmaf(sv[wib][k], sW2[k * 40 + lane], acc);
            g2[(unsigned)wid * 40u + (unsigned)lane] = acc;
        }
    }
}

// layer-2 aggregation (F=40, fp16 table) + bias + log_softmax -> output.
__global__ void k_agg40_lsm(const _Float16* __restrict__ hd2, const int2* __restrict__ cw,
                            const float* __restrict__ dinv, const float* __restrict__ selfc,
                            const float* __restrict__ b, const int* __restrict__ row_ptr,
                            const int* __restrict__ lend,
                            float* __restrict__ out, int n)
{
    constexpr int F = 40;
    int gid  = blockIdx.x * blockDim.x + threadIdx.x;
    int wid  = gid >> 6;
    int lane = threadIdx.x & 63;
    if (wid >= n) return;
    int beg = row_ptr[wid], le = lend[wid];
    bool active = (lane < F);
    // independent loads issued before the gather
    float hs = active ? (float)hd2[(unsigned)wid * 40u + (unsigned)lane] : 0.0f;
    float dv = dinv[wid];
    float sc = selfc[wid];
    float bl = active ? b[lane] : 0.0f;
    float accf = agg_core_t<F>((const half4*)hd2, cw, beg, le, lane);
    float v = 0.0f;
    if (active) v = dv * accf + sc * hs + bl;
    float m = active ? v : -__builtin_inff();
#pragma unroll
    for (int off = 32; off > 0; off >>= 1) m = fmaxf(m, __shfl_xor(m, off));
    float ex = active ? __expf(v - m) : 0.0f;
    float s = ex;
#pragma unroll
    for (int off = 32; off > 0; off >>= 1) s += __shfl_xor(s, off);
    if (active) out[(size_t)wid * F + lane] = v - m - __logf(s);
}

extern "C" void kernel_launch(void* const* d_in, const int* in_sizes, int n_in,
                              void* d_out, int out_size, void* d_ws, size_t ws_size,
                              hipStream_t stream)
{
    const float* x  = (const float*)d_in[0];
    const int*   ei = (const int*)d_in[1];
    const float* W1 = (const float*)d_in[2];
    const float* b1 = (const float*)d_in[3];
    const float* W2 = (const float*)d_in[4];
    const float* b2 = (const float*)d_in[5];
    float* out = (float*)d_out;

    const int N = in_sizes[0] / 64;   // 50000
    const int E = in_sizes[1] / 2;    // 800000
    const int* row = ei;
    const int* col = ei + E;

    const int nblkA = (E + EPB - 1) / EPB;       // edge blocks for bucket sort
    const int nbuck = (N + RPB - 1) / RPB;       // buckets (rows/128)

    char* p = (char*)d_ws;
    auto alloc = [&](size_t bytes) -> char* {
        char* r = p; p += (bytes + 255) & ~(size_t)255; return r;
    };
    float*     fn     = (float*)alloc((size_t)N * 64 * 4);     // normalized x
    float*     dinv   = (float*)alloc((size_t)N * 4);
    float*     selfc  = (float*)alloc((size_t)N * 4);
    float*     hd1    = (float*)alloc((size_t)N * 64 * 4);     // x@W1, then *di in-place
    float*     g2     = (float*)alloc((size_t)N * 40 * 4);     // hrelu@W2 (fp32)
    _Float16*  hd2    = (_Float16*)alloc((size_t)N * 40 * 2);  // g2*di2 (fp16)
    float*     fnh    = (float*)alloc((size_t)N * 64 * 4);     // normalized hrelu
    int*       rptr   = (int*)alloc((size_t)(N + 1) * 4);
    int*       lendv  = (int*)alloc((size_t)N * 4);
    int*       col_s  = (int*)alloc((size_t)E * 4);
    int2*      cw     = (int2*)alloc((size_t)E * 8);           // packed (col,w)
    int*       ebuf   = (int*)alloc((size_t)nbuck * CAPB * 4); // slack-segmented
    int*       gcur   = (int*)alloc((size_t)nbuck * 4);

    const int TB = 256;
    int blk_nodeWave = (N * 64 + TB - 1) / TB;   // 12500 (norm range, 1 wave/node)
    int blk_gemm     = (N + 3) / 4;              // 12500 (gemm range, 4 rows/block)
    int blk_node4    = (N + 3) / 4;              // 12500
    int blk_node8    = (N + 7) / 8;              // 6250

    hipMemsetAsync(gcur, 0, (size_t)nbuck * 4, stream);

    // ---- CSR build + x normalization + W1 GEMM (fused 3-range launch)
    k_bscat_norm_gemm<<<nblkA + blk_nodeWave + blk_gemm, TB, 0, stream>>>(
        row, col, gcur, ebuf, E, nbuck, nblkA, blk_nodeWave, x, fn, W1, hd1, N);
    k_csr<<<nbuck, TB, 0, stream>>>(ebuf, gcur, rptr, col_s, N, E, nbuck);

    // ---- layer 1 (att epilogue scales hd1 *= di in place)
    k_att<<<blk_node4, TB, 0, stream>>>(fn, rptr, col_s, cw, lendv, dinv, selfc,
                                        (const float*)nullptr, (_Float16*)nullptr,
                                        hd1, N);
    k_agg64<<<blk_node8, TB, 0, stream>>>(hd1, cw, dinv, selfc, b1,
                                          rptr, lendv, W2, g2, fnh, N);

    // ---- layer 2 (att epilogue scales g2 -> hd2; agg40 finishes)
    k_att<<<blk_node4, TB, 0, stream>>>(fnh, rptr, col_s, cw, lendv, dinv, selfc,
                                        g2, hd2, (float*)nullptr, N);
    k_agg40_lsm<<<blk_nodeWave, TB, 0, stream>>>(hd2, cw, dinv, selfc, b2,
                                                 rptr, lendv, out, N);
}